// Round 9
// baseline (298.299 us; speedup 1.0000x reference)
//
#include <hip/hip_runtime.h>
#include <cstdint>

typedef unsigned short u16;
typedef __attribute__((ext_vector_type(8))) short bf16x8;   // 8 bf16 = 4 VGPRs
typedef __attribute__((ext_vector_type(4))) float f32x4;

#define S_LEN 2048
#define HDIM  1024
#define NHEAD 16

__device__ __forceinline__ float bf2f(u16 u){ return __uint_as_float(((uint32_t)u) << 16); }
__device__ __forceinline__ u16 f2bf(float f){
  uint32_t x = __float_as_uint(f);
  return (u16)((x + 0x7fffu + ((x >> 16) & 1u)) >> 16);   // RNE
}

// async global->LDS 16B (m97 idiom). LDS dest is wave-uniform base + lane*16.
__device__ __forceinline__ void gload_lds16(const void* g, void* l){
  __builtin_amdgcn_global_load_lds((const __attribute__((address_space(1))) void*)g,
                                   (__attribute__((address_space(3))) void*)l, 16, 0, 0);
}

// ---------------- f32 -> bf16 elementwise, batched over {q,k,v} via blockIdx.y ----------------
__global__ __launch_bounds__(256) void k_cvt3(const float* __restrict__ q, const float* __restrict__ k,
                                              const float* __restrict__ v, u16* __restrict__ oq,
                                              u16* __restrict__ ok, u16* __restrict__ ov){
  int z = blockIdx.y;
  const float* in = z == 0 ? q : (z == 1 ? k : v);
  u16* out = z == 0 ? oq : (z == 1 ? ok : ov);
  int i = blockIdx.x * 256 + threadIdx.x;     // 8 elems/thread, 4M elems total
  float4 f0 = *(const float4*)&in[(size_t)i * 8];
  float4 f1 = *(const float4*)&in[(size_t)i * 8 + 4];
  bf16x8 o;
  o[0] = (short)f2bf(f0.x); o[1] = (short)f2bf(f0.y);
  o[2] = (short)f2bf(f0.z); o[3] = (short)f2bf(f0.w);
  o[4] = (short)f2bf(f1.x); o[5] = (short)f2bf(f1.y);
  o[6] = (short)f2bf(f1.z); o[7] = (short)f2bf(f1.w);
  *(bf16x8*)&out[(size_t)i * 8] = o;
}

// ---------------- weight transpose + cvt, batched over 4 weights: wt[n][k] = w[k][n] ----------------
__global__ __launch_bounds__(256) void k_tr_w4(const float* __restrict__ w0, const float* __restrict__ w1,
                                               const float* __restrict__ w2, const float* __restrict__ w3,
                                               u16* __restrict__ o0, u16* __restrict__ o1,
                                               u16* __restrict__ o2, u16* __restrict__ o3){
  int z = blockIdx.z;
  const float* in = z == 0 ? w0 : (z == 1 ? w1 : (z == 2 ? w2 : w3));
  u16* out = z == 0 ? o0 : (z == 1 ? o1 : (z == 2 ? o2 : o3));
  __shared__ float t[64][65];
  int r0 = threadIdx.x >> 6;          // 0..3
  int c  = threadIdx.x & 63;
  int bx = blockIdx.x * 64, by = blockIdx.y * 64;
  #pragma unroll
  for (int i = 0; i < 64; i += 4) t[r0 + i][c] = in[(size_t)(by + r0 + i) * 1024 + bx + c];
  __syncthreads();
  #pragma unroll
  for (int i = 0; i < 64; i += 4) out[(size_t)(bx + r0 + i) * 1024 + by + c] = f2bf(t[c][r0 + i]);
}

// ---------------- v transpose (bf16->bf16): vt[b*16+h][d][s] = v[b][s][h*64+d] ----------------
__global__ __launch_bounds__(256) void k_tr_v(const u16* __restrict__ v, u16* __restrict__ vt){
  __shared__ u16 t[64][65];
  int r0 = threadIdx.x >> 6, c = threadIdx.x & 63;
  int s0 = blockIdx.x * 64;
  int bh = blockIdx.y;                // b*16+h
  int b = bh >> 4, h = bh & 15;
  const u16* src = v + (size_t)b * S_LEN * HDIM + h * 64;
  #pragma unroll
  for (int i = 0; i < 64; i += 4) t[r0 + i][c] = src[(size_t)(s0 + r0 + i) * HDIM + c];
  __syncthreads();
  u16* dst = vt + (size_t)bh * 64 * S_LEN + s0;
  #pragma unroll
  for (int i = 0; i < 64; i += 4) dst[(size_t)(r0 + i) * S_LEN + c] = t[c][r0 + i];
}

// ---------------- fused QKV GEMM: z in {0,1,2}; C[4096][1024] = A_z @ Wt_z^T, (acc+bias)*scale ----
__global__ __launch_bounds__(256) void k_gemm_qkv(const u16* __restrict__ A0, const u16* __restrict__ A1,
                                                  const u16* __restrict__ A2,
                                                  const u16* __restrict__ W0, const u16* __restrict__ W1,
                                                  const u16* __restrict__ W2,
                                                  const float* __restrict__ b0, const float* __restrict__ b1,
                                                  const float* __restrict__ b2,
                                                  u16* __restrict__ C0, u16* __restrict__ C1,
                                                  u16* __restrict__ C2)
{
  int z = blockIdx.z;
  const u16* A  = z == 0 ? A0 : (z == 1 ? A1 : A2);
  const u16* Wt = z == 0 ? W0 : (z == 1 ? W1 : W2);
  const float* bias = z == 0 ? b0 : (z == 1 ? b1 : b2);
  u16* C = z == 0 ? C0 : (z == 1 ? C1 : C2);
  float scale = z == 0 ? (1.0f / 64.0f) : 1.0f;   // fold 1/(8*8) into q

  __shared__ u16 As[128 * 32];       // unpadded: lane-linear for global_load_lds
  __shared__ u16 Bs[128 * 32];
  const int K = 1024, N = 1024;
  int tid = threadIdx.x;
  int lane = tid & 63, wave = tid >> 6;
  int quad = lane >> 4, c16 = lane & 15;
  int wm = wave >> 1, wn = wave & 1;
  int m0 = blockIdx.x * 128, n0 = blockIdx.y * 128;

  f32x4 acc[4][4] = {};

  for (int k0 = 0; k0 < K; k0 += 32) {
    #pragma unroll
    for (int i = 0; i < 2; i++) {
      int slot = tid + i * 256;                 // 128 rows x 4 chunks(16B)
      int r = slot >> 2, cc = (slot & 3) * 8;
      gload_lds16(&A [(size_t)(m0 + r) * K + k0 + cc], &As[slot * 8]);
      gload_lds16(&Wt[(size_t)(n0 + r) * K + k0 + cc], &Bs[slot * 8]);
    }
    __syncthreads();
    bf16x8 af[4], bfr[4];
    #pragma unroll
    for (int mt = 0; mt < 4; mt++) af[mt]  = *(const bf16x8*)&As[(wm * 64 + mt * 16 + c16) * 32 + quad * 8];
    #pragma unroll
    for (int nt = 0; nt < 4; nt++) bfr[nt] = *(const bf16x8*)&Bs[(wn * 64 + nt * 16 + c16) * 32 + quad * 8];
    #pragma unroll
    for (int mt = 0; mt < 4; mt++)
      #pragma unroll
      for (int nt = 0; nt < 4; nt++)
        acc[mt][nt] = __builtin_amdgcn_mfma_f32_16x16x32_bf16(af[mt], bfr[nt], acc[mt][nt], 0, 0, 0);
    __syncthreads();
  }

  #pragma unroll
  for (int nt = 0; nt < 4; nt++) {
    int gc = n0 + wn * 64 + nt * 16 + c16;
    float bv = bias[gc];
    #pragma unroll
    for (int mt = 0; mt < 4; mt++)
      #pragma unroll
      for (int r = 0; r < 4; r++) {
        int gr = m0 + wm * 64 + mt * 16 + quad * 4 + r;
        C[(size_t)gr * N + gc] = f2bf((acc[mt][nt][r] + bv) * scale);
      }
  }
}

// ---------------- O-proj GEMM: 128x64 tiles (512 blocks, 2/CU), f32 out ----------------
__global__ __launch_bounds__(256) void k_gemm_o(const u16* __restrict__ A, const u16* __restrict__ Wt,
                                                const float* __restrict__ bias, float* __restrict__ C)
{
  __shared__ u16 As[128 * 32];
  __shared__ u16 Bs[64 * 32];
  const int K = 1024, N = 1024;
  int tid = threadIdx.x;
  int lane = tid & 63, wave = tid >> 6;
  int quad = lane >> 4, c16 = lane & 15;
  int wm = wave >> 1, wn = wave & 1;            // wave tile 64x32
  int m0 = blockIdx.x * 128, n0 = blockIdx.y * 64;

  f32x4 acc[4][2] = {};

  for (int k0 = 0; k0 < K; k0 += 32) {
    #pragma unroll
    for (int i = 0; i < 2; i++) {                // A: 128 rows x 4 chunks = 512 chunks
      int slot = tid + i * 256;
      int r = slot >> 2, cc = (slot & 3) * 8;
      gload_lds16(&A[(size_t)(m0 + r) * K + k0 + cc], &As[slot * 8]);
    }
    {                                            // B: 64 rows x 4 chunks = 256 chunks
      int r = tid >> 2, cc = (tid & 3) * 8;
      gload_lds16(&Wt[(size_t)(n0 + r) * K + k0 + cc], &Bs[tid * 8]);
    }
    __syncthreads();
    bf16x8 af[4], bfr[2];
    #pragma unroll
    for (int mt = 0; mt < 4; mt++) af[mt]  = *(const bf16x8*)&As[(wm * 64 + mt * 16 + c16) * 32 + quad * 8];
    #pragma unroll
    for (int nt = 0; nt < 2; nt++) bfr[nt] = *(const bf16x8*)&Bs[(wn * 32 + nt * 16 + c16) * 32 + quad * 8];
    #pragma unroll
    for (int mt = 0; mt < 4; mt++)
      #pragma unroll
      for (int nt = 0; nt < 2; nt++)
        acc[mt][nt] = __builtin_amdgcn_mfma_f32_16x16x32_bf16(af[mt], bfr[nt], acc[mt][nt], 0, 0, 0);
    __syncthreads();
  }

  #pragma unroll
  for (int nt = 0; nt < 2; nt++) {
    int gc = n0 + wn * 32 + nt * 16 + c16;
    float bv = bias[gc];
    #pragma unroll
    for (int mt = 0; mt < 4; mt++)
      #pragma unroll
      for (int r = 0; r < 4; r++) {
        int gr = m0 + wm * 64 + mt * 16 + quad * 4 + r;
        C[(size_t)gr * N + gc] = acc[mt][nt][r] + bv;
      }
  }
}

// ---------------- flash attention, barrier-free K-loop -------------------------------------------
// K and VT MFMA fragments are 16B-contiguous in global memory -> load straight to VGPRs
// (no LDS staging, no __syncthreads in the loop). K-frags double-buffered in registers.
// 128 q-rows/block, 4 waves x M=32; grid 16x16x2. Ps round-trip is wave-private.
__global__ __launch_bounds__(256, 2) void k_attn(const u16* __restrict__ Qm,
                                                 const u16* __restrict__ Km,
                                                 const u16* __restrict__ VTm,
                                                 const float* __restrict__ mask,
                                                 u16* __restrict__ Om)
{
  __shared__ u16 Ps[128][72];        // wave-private 32-row bands
  __shared__ float Msall[S_LEN];     // mask additive terms for whole row, staged once
  int tid = threadIdx.x;
  int lane = tid & 63, wave = tid >> 6;         // wave 0..3
  int quad = lane >> 4, c16 = lane & 15;
  int qb = blockIdx.x, h = blockIdx.y, b = blockIdx.z;
  const size_t SH = (size_t)S_LEN * HDIM;
  const u16* Qbase  = Qm + (size_t)b * SH + (size_t)qb * 128 * HDIM + h * 64;
  const u16* Kbase  = Km + (size_t)b * SH + h * 64;
  const u16* VTbase = VTm + (size_t)(b * NHEAD + h) * 64 * S_LEN;
  const float* Mbase = mask + (size_t)b * S_LEN;

  for (int i = tid; i < S_LEN; i += 256) Msall[i] = (1.0f - Mbase[i]) * (-1.25e9f);   // (-1e10)/8

  int qw0 = wave * 32;                          // wave owns 32 q-rows of the 128

  // Q fragments (loop-invariant): A[m][k], rows qw0+mt*16+c16, k = kk*32+quad*8+j
  bf16x8 aq[2][2];
  #pragma unroll
  for (int mt = 0; mt < 2; mt++)
    #pragma unroll
    for (int kk = 0; kk < 2; kk++)
      aq[mt][kk] = *(const bf16x8*)&Qbase[(size_t)(qw0 + mt * 16 + c16) * HDIM + kk * 32 + quad * 8];

  f32x4 oacc[2][4] = {};
  float lsum[2][4] = {};

  // first K fragment set (tile 0): B[n=s_local][k=d] is 16B-contiguous in d
  bf16x8 bkA[2][4], bkB[2][4];
  #pragma unroll
  for (int kk = 0; kk < 2; kk++)
    #pragma unroll
    for (int nt = 0; nt < 4; nt++)
      bkA[kk][nt] = *(const bf16x8*)&Kbase[(size_t)(nt * 16 + c16) * HDIM + kk * 32 + quad * 8];

  __syncthreads();                              // Msall visible (only barrier in the kernel)

  auto body = [&](int kt, bf16x8 (&cur)[2][4], bf16x8 (&nxt)[2][4]) {
    int s0 = kt * 64;
    // VT fragments for this tile: B[n=d][k=s] is 16B-contiguous in s (issued early, used last)
    bf16x8 vb[2][4];
    #pragma unroll
    for (int kk = 0; kk < 2; kk++)
      #pragma unroll
      for (int nt = 0; nt < 4; nt++)
        vb[kk][nt] = *(const bf16x8*)&VTbase[(size_t)(nt * 16 + c16) * S_LEN + s0 + kk * 32 + quad * 8];

    // S = Q K^T  (M=32, N=64, K=64)
    f32x4 sacc[2][4] = {};
    #pragma unroll
    for (int kk = 0; kk < 2; kk++)
      #pragma unroll
      for (int mt = 0; mt < 2; mt++)
        #pragma unroll
        for (int nt = 0; nt < 4; nt++)
          sacc[mt][nt] = __builtin_amdgcn_mfma_f32_16x16x32_bf16(aq[mt][kk], cur[kk][nt], sacc[mt][nt], 0, 0, 0);

    // prefetch next tile's K fragments (latency covered by exp + PV below)
    if (kt + 1 < S_LEN / 64) {
      int s1 = s0 + 64;
      #pragma unroll
      for (int kk = 0; kk < 2; kk++)
        #pragma unroll
        for (int nt = 0; nt < 4; nt++)
          nxt[kk][nt] = *(const bf16x8*)&Kbase[(size_t)(s1 + nt * 16 + c16) * HDIM + kk * 32 + quad * 8];
    }

    // P = exp(S + maskterm); wave-private Ps rows (same-wave DS order, no barrier)
    #pragma unroll
    for (int nt = 0; nt < 4; nt++) {
      float madd = Msall[s0 + nt * 16 + c16];
      #pragma unroll
      for (int mt = 0; mt < 2; mt++)
        #pragma unroll
        for (int r = 0; r < 4; r++) {
          float p = __expf(sacc[mt][nt][r] + madd);
          lsum[mt][r] += p;
          Ps[qw0 + mt * 16 + quad * 4 + r][nt * 16 + c16] = f2bf(p);
        }
    }

    // O += P V
    #pragma unroll
    for (int kk = 0; kk < 2; kk++) {
      bf16x8 pa[2];
      #pragma unroll
      for (int mt = 0; mt < 2; mt++) pa[mt] = *(const bf16x8*)&Ps[qw0 + mt * 16 + c16][kk * 32 + quad * 8];
      #pragma unroll
      for (int mt = 0; mt < 2; mt++)
        #pragma unroll
        for (int nt = 0; nt < 4; nt++)
          oacc[mt][nt] = __builtin_amdgcn_mfma_f32_16x16x32_bf16(pa[mt], vb[kk][nt], oacc[mt][nt], 0, 0, 0);
    }
  };

  for (int kt = 0; kt < S_LEN / 64; kt += 2) {  // register ping-pong on K fragments
    body(kt,     bkA, bkB);
    body(kt + 1, bkB, bkA);
  }

  // row-sum l: reduce across the 16 c16-lanes
  #pragma unroll
  for (int mt = 0; mt < 2; mt++)
    #pragma unroll
    for (int r = 0; r < 4; r++) {
      float v = lsum[mt][r];
      v += __shfl_xor(v, 1); v += __shfl_xor(v, 2); v += __shfl_xor(v, 4); v += __shfl_xor(v, 8);
      lsum[mt][r] = v;
    }

  u16* Obase = Om + (size_t)b * SH + (size_t)qb * 128 * HDIM + h * 64;
  #pragma unroll
  for (int mt = 0; mt < 2; mt++)
    #pragma unroll
    for (int nt = 0; nt < 4; nt++)
      #pragma unroll
      for (int r = 0; r < 4; r++) {
        int lr = qw0 + mt * 16 + quad * 4 + r;
        Obase[(size_t)lr * HDIM + nt * 16 + c16] = f2bf(oacc[mt][nt][r] / lsum[mt][r]);
      }
}

extern "C" void kernel_launch(void* const* d_in, const int* in_sizes, int n_in,
                              void* d_out, int out_size, void* d_ws, size_t ws_size,
                              hipStream_t stream)
{
  (void)in_sizes; (void)n_in; (void)out_size; (void)ws_size;
  const float* q_in = (const float*)d_in[0];
  const float* k_in = (const float*)d_in[1];
  const float* v_in = (const float*)d_in[2];
  const float* mask = (const float*)d_in[3];
  const float* wq   = (const float*)d_in[4];
  const float* bq   = (const float*)d_in[5];
  const float* wk   = (const float*)d_in[6];
  const float* bk   = (const float*)d_in[7];
  const float* wv   = (const float*)d_in[8];
  const float* bv   = (const float*)d_in[9];
  const float* wo   = (const float*)d_in[10];
  const float* bo   = (const float*)d_in[11];

  u16* ws  = (u16*)d_ws;                 // bf16 elems: 4x1M wt + 3x4M in + 5x4M acts = 72 MB
  u16* wqt = ws;
  u16* wkt = wqt + (1u << 20);
  u16* wvt = wkt + (1u << 20);
  u16* wot = wvt + (1u << 20);
  u16* qi_ = wot + (1u << 20);
  u16* ki_ = qi_ + (4u << 20);
  u16* vi_ = ki_ + (4u << 20);
  u16* qb_ = vi_ + (4u << 20);
  u16* kb_ = qb_ + (4u << 20);
  u16* vb_ = kb_ + (4u << 20);
  u16* vtb = vb_ + (4u << 20);
  u16* ob_ = vtb + (4u << 20);

  dim3 blk(256);
  k_cvt3<<<dim3(2048, 3), blk, 0, stream>>>(q_in, k_in, v_in, qi_, ki_, vi_);
  k_tr_w4<<<dim3(16, 16, 4), blk, 0, stream>>>(wq, wk, wv, wo, wqt, wkt, wvt, wot);
  k_gemm_qkv<<<dim3(32, 8, 3), blk, 0, stream>>>(qi_, ki_, vi_, wqt, wkt, wvt, bq, bk, bv, qb_, kb_, vb_);
  k_tr_v<<<dim3(32, 32), blk, 0, stream>>>(vb_, vtb);
  k_attn<<<dim3(16, 16, 2), blk, 0, stream>>>(qb_, kb_, vtb, mask, ob_);
  k_gemm_o<<<dim3(32, 16), blk, 0, stream>>>(ob_, wot, bo, (float*)d_out);
}

// Round 10
// 239.838 us; speedup vs baseline: 1.2438x; 1.2438x over previous
//
#include <hip/hip_runtime.h>
#include <cstdint>

typedef unsigned short u16;
typedef __attribute__((ext_vector_type(8))) short bf16x8;   // 8 bf16 = 4 VGPRs
typedef __attribute__((ext_vector_type(4))) float f32x4;

#define S_LEN 2048
#define HDIM  1024
#define NHEAD 16

__device__ __forceinline__ float bf2f(u16 u){ return __uint_as_float(((uint32_t)u) << 16); }
__device__ __forceinline__ u16 f2bf(float f){
  uint32_t x = __float_as_uint(f);
  return (u16)((x + 0x7fffu + ((x >> 16) & 1u)) >> 16);   // RNE
}

// async global->LDS 16B (m97 idiom). LDS dest is wave-uniform base + lane*16.
__device__ __forceinline__ void gload_lds16(const void* g, void* l){
  __builtin_amdgcn_global_load_lds((const __attribute__((address_space(1))) void*)g,
                                   (__attribute__((address_space(3))) void*)l, 16, 0, 0);
}

// ---------------- f32 -> bf16 elementwise, batched over {q,k,v} via blockIdx.y ----------------
__global__ __launch_bounds__(256) void k_cvt3(const float* __restrict__ q, const float* __restrict__ k,
                                              const float* __restrict__ v, u16* __restrict__ oq,
                                              u16* __restrict__ ok, u16* __restrict__ ov){
  int z = blockIdx.y;
  const float* in = z == 0 ? q : (z == 1 ? k : v);
  u16* out = z == 0 ? oq : (z == 1 ? ok : ov);
  int i = blockIdx.x * 256 + threadIdx.x;     // 8 elems/thread, 4M elems total
  float4 f0 = *(const float4*)&in[(size_t)i * 8];
  float4 f1 = *(const float4*)&in[(size_t)i * 8 + 4];
  bf16x8 o;
  o[0] = (short)f2bf(f0.x); o[1] = (short)f2bf(f0.y);
  o[2] = (short)f2bf(f0.z); o[3] = (short)f2bf(f0.w);
  o[4] = (short)f2bf(f1.x); o[5] = (short)f2bf(f1.y);
  o[6] = (short)f2bf(f1.z); o[7] = (short)f2bf(f1.w);
  *(bf16x8*)&out[(size_t)i * 8] = o;
}

// ---------------- weight transpose + cvt, batched over 4 weights: wt[n][k] = w[k][n] ----------------
__global__ __launch_bounds__(256) void k_tr_w4(const float* __restrict__ w0, const float* __restrict__ w1,
                                               const float* __restrict__ w2, const float* __restrict__ w3,
                                               u16* __restrict__ o0, u16* __restrict__ o1,
                                               u16* __restrict__ o2, u16* __restrict__ o3){
  int z = blockIdx.z;
  const float* in = z == 0 ? w0 : (z == 1 ? w1 : (z == 2 ? w2 : w3));
  u16* out = z == 0 ? o0 : (z == 1 ? o1 : (z == 2 ? o2 : o3));
  __shared__ float t[64][65];
  int r0 = threadIdx.x >> 6;          // 0..3
  int c  = threadIdx.x & 63;
  int bx = blockIdx.x * 64, by = blockIdx.y * 64;
  #pragma unroll
  for (int i = 0; i < 64; i += 4) t[r0 + i][c] = in[(size_t)(by + r0 + i) * 1024 + bx + c];
  __syncthreads();
  #pragma unroll
  for (int i = 0; i < 64; i += 4) out[(size_t)(bx + r0 + i) * 1024 + by + c] = f2bf(t[c][r0 + i]);
}

// ---------------- v transpose (bf16->bf16): vt[b*16+h][d][s] = v[b][s][h*64+d] ----------------
__global__ __launch_bounds__(256) void k_tr_v(const u16* __restrict__ v, u16* __restrict__ vt){
  __shared__ u16 t[64][65];
  int r0 = threadIdx.x >> 6, c = threadIdx.x & 63;
  int s0 = blockIdx.x * 64;
  int bh = blockIdx.y;                // b*16+h
  int b = bh >> 4, h = bh & 15;
  const u16* src = v + (size_t)b * S_LEN * HDIM + h * 64;
  #pragma unroll
  for (int i = 0; i < 64; i += 4) t[r0 + i][c] = src[(size_t)(s0 + r0 + i) * HDIM + c];
  __syncthreads();
  u16* dst = vt + (size_t)bh * 64 * S_LEN + s0;
  #pragma unroll
  for (int i = 0; i < 64; i += 4) dst[(size_t)(r0 + i) * S_LEN + c] = t[c][r0 + i];
}

// ---------------- fused QKV GEMM: z in {0,1,2}; C[4096][1024] = A_z @ Wt_z^T, (acc+bias)*scale ----
__global__ __launch_bounds__(256) void k_gemm_qkv(const u16* __restrict__ A0, const u16* __restrict__ A1,
                                                  const u16* __restrict__ A2,
                                                  const u16* __restrict__ W0, const u16* __restrict__ W1,
                                                  const u16* __restrict__ W2,
                                                  const float* __restrict__ b0, const float* __restrict__ b1,
                                                  const float* __restrict__ b2,
                                                  u16* __restrict__ C0, u16* __restrict__ C1,
                                                  u16* __restrict__ C2)
{
  int z = blockIdx.z;
  const u16* A  = z == 0 ? A0 : (z == 1 ? A1 : A2);
  const u16* Wt = z == 0 ? W0 : (z == 1 ? W1 : W2);
  const float* bias = z == 0 ? b0 : (z == 1 ? b1 : b2);
  u16* C = z == 0 ? C0 : (z == 1 ? C1 : C2);
  float scale = z == 0 ? (1.0f / 64.0f) : 1.0f;   // fold 1/(8*8) into q

  __shared__ u16 As[128 * 32];       // unpadded: lane-linear for global_load_lds
  __shared__ u16 Bs[128 * 32];
  const int K = 1024, N = 1024;
  int tid = threadIdx.x;
  int lane = tid & 63, wave = tid >> 6;
  int quad = lane >> 4, c16 = lane & 15;
  int wm = wave >> 1, wn = wave & 1;
  int m0 = blockIdx.x * 128, n0 = blockIdx.y * 128;

  f32x4 acc[4][4] = {};

  for (int k0 = 0; k0 < K; k0 += 32) {
    #pragma unroll
    for (int i = 0; i < 2; i++) {
      int slot = tid + i * 256;                 // 128 rows x 4 chunks(16B)
      int r = slot >> 2, cc = (slot & 3) * 8;
      gload_lds16(&A [(size_t)(m0 + r) * K + k0 + cc], &As[slot * 8]);
      gload_lds16(&Wt[(size_t)(n0 + r) * K + k0 + cc], &Bs[slot * 8]);
    }
    __syncthreads();
    bf16x8 af[4], bfr[4];
    #pragma unroll
    for (int mt = 0; mt < 4; mt++) af[mt]  = *(const bf16x8*)&As[(wm * 64 + mt * 16 + c16) * 32 + quad * 8];
    #pragma unroll
    for (int nt = 0; nt < 4; nt++) bfr[nt] = *(const bf16x8*)&Bs[(wn * 64 + nt * 16 + c16) * 32 + quad * 8];
    #pragma unroll
    for (int mt = 0; mt < 4; mt++)
      #pragma unroll
      for (int nt = 0; nt < 4; nt++)
        acc[mt][nt] = __builtin_amdgcn_mfma_f32_16x16x32_bf16(af[mt], bfr[nt], acc[mt][nt], 0, 0, 0);
    __syncthreads();
  }

  #pragma unroll
  for (int nt = 0; nt < 4; nt++) {
    int gc = n0 + wn * 64 + nt * 16 + c16;
    float bv = bias[gc];
    #pragma unroll
    for (int mt = 0; mt < 4; mt++)
      #pragma unroll
      for (int r = 0; r < 4; r++) {
        int gr = m0 + wm * 64 + mt * 16 + quad * 4 + r;
        C[(size_t)gr * N + gc] = f2bf((acc[mt][nt][r] + bv) * scale);
      }
  }
}

// ---------------- O-proj GEMM: 128x64 tiles (512 blocks, 2/CU), f32 out ----------------
__global__ __launch_bounds__(256) void k_gemm_o(const u16* __restrict__ A, const u16* __restrict__ Wt,
                                                const float* __restrict__ bias, float* __restrict__ C)
{
  __shared__ u16 As[128 * 32];
  __shared__ u16 Bs[64 * 32];
  const int K = 1024, N = 1024;
  int tid = threadIdx.x;
  int lane = tid & 63, wave = tid >> 6;
  int quad = lane >> 4, c16 = lane & 15;
  int wm = wave >> 1, wn = wave & 1;            // wave tile 64x32
  int m0 = blockIdx.x * 128, n0 = blockIdx.y * 64;

  f32x4 acc[4][2] = {};

  for (int k0 = 0; k0 < K; k0 += 32) {
    #pragma unroll
    for (int i = 0; i < 2; i++) {                // A: 128 rows x 4 chunks = 512 chunks
      int slot = tid + i * 256;
      int r = slot >> 2, cc = (slot & 3) * 8;
      gload_lds16(&A[(size_t)(m0 + r) * K + k0 + cc], &As[slot * 8]);
    }
    {                                            // B: 64 rows x 4 chunks = 256 chunks
      int r = tid >> 2, cc = (tid & 3) * 8;
      gload_lds16(&Wt[(size_t)(n0 + r) * K + k0 + cc], &Bs[tid * 8]);
    }
    __syncthreads();
    bf16x8 af[4], bfr[2];
    #pragma unroll
    for (int mt = 0; mt < 4; mt++) af[mt]  = *(const bf16x8*)&As[(wm * 64 + mt * 16 + c16) * 32 + quad * 8];
    #pragma unroll
    for (int nt = 0; nt < 2; nt++) bfr[nt] = *(const bf16x8*)&Bs[(wn * 32 + nt * 16 + c16) * 32 + quad * 8];
    #pragma unroll
    for (int mt = 0; mt < 4; mt++)
      #pragma unroll
      for (int nt = 0; nt < 2; nt++)
        acc[mt][nt] = __builtin_amdgcn_mfma_f32_16x16x32_bf16(af[mt], bfr[nt], acc[mt][nt], 0, 0, 0);
    __syncthreads();
  }

  #pragma unroll
  for (int nt = 0; nt < 2; nt++) {
    int gc = n0 + wn * 32 + nt * 16 + c16;
    float bv = bias[gc];
    #pragma unroll
    for (int mt = 0; mt < 4; mt++)
      #pragma unroll
      for (int r = 0; r < 4; r++) {
        int gr = m0 + wm * 64 + mt * 16 + quad * 4 + r;
        C[(size_t)gr * N + gc] = acc[mt][nt][r] + bv;
      }
  }
}

// ---------------- flash attention: 128 q-rows/block, 4 waves x M=32, DOUBLE-BUFFERED staging -----
// Prefetch tile kt+1 (async global_load_lds) at top of iter kt; compute on buffer kt&1; the single
// end-of-iter barrier's vmcnt(0) drain lands after a full compute phase -> staging latency hidden.
__global__ __launch_bounds__(256, 2) void k_attn(const u16* __restrict__ Qm,
                                                 const u16* __restrict__ Km,
                                                 const u16* __restrict__ VTm,
                                                 const float* __restrict__ mask,
                                                 u16* __restrict__ Om)
{
  __shared__ u16 Ks[2][64 * 72];     // 72 = 9 chunks of 16B
  __shared__ u16 VTs[2][64 * 72];
  __shared__ u16 Ps[128][72];        // wave-private 32-row bands
  __shared__ float Msall[S_LEN];     // mask additive terms, staged once
  int tid = threadIdx.x;
  int lane = tid & 63, wave = tid >> 6;         // wave 0..3
  int quad = lane >> 4, c16 = lane & 15;
  int qb = blockIdx.x, h = blockIdx.y, b = blockIdx.z;
  const size_t SH = (size_t)S_LEN * HDIM;
  const u16* Qbase  = Qm + (size_t)b * SH + (size_t)qb * 128 * HDIM + h * 64;
  const u16* Kbase  = Km + (size_t)b * SH + h * 64;
  const u16* VTbase = VTm + (size_t)(b * NHEAD + h) * 64 * S_LEN;
  const float* Mbase = mask + (size_t)b * S_LEN;

  // async stage K(64x64)+VT(64x64) for tile at s0 into buffer bb (1152 chunks over 5x256,
  // branch boundaries on wave edges; chunk 8 of each 9-chunk row is pad -> dummy load)
  auto stage = [&](int s0, int bb) {
    #pragma unroll
    for (int i = 0; i < 5; i++) {
      int c = i * 256 + tid;
      if (c < 576) {
        int r = c / 9, cc = c - r * 9;
        int col = (cc == 8) ? 0 : cc * 8;
        gload_lds16(&Kbase[(size_t)(s0 + r) * HDIM + col], &Ks[bb][c * 8]);
      } else if (c < 1152) {
        int c2 = c - 576;
        int r = c2 / 9, cc = c2 - r * 9;
        int col = (cc == 8) ? 0 : cc * 8;
        gload_lds16(&VTbase[(size_t)r * S_LEN + s0 + col], &VTs[bb][c2 * 8]);
      }
    }
  };

  for (int i = tid; i < S_LEN; i += 256) Msall[i] = (1.0f - Mbase[i]) * (-1.25e9f);   // (-1e10)/8

  int qw0 = wave * 32;                          // wave owns 32 q-rows of the 128

  // Q fragments in registers (loop-invariant): A[m][k], rows qw0+mt*16+c16, k = kk*32+quad*8+j
  bf16x8 aq[2][2];
  #pragma unroll
  for (int mt = 0; mt < 2; mt++)
    #pragma unroll
    for (int kk = 0; kk < 2; kk++)
      aq[mt][kk] = *(const bf16x8*)&Qbase[(size_t)(qw0 + mt * 16 + c16) * HDIM + kk * 32 + quad * 8];

  f32x4 oacc[2][4] = {};
  float lsum[2][4] = {};

  stage(0, 0);
  __syncthreads();                              // tile 0 + Msall ready

  for (int kt = 0; kt < S_LEN / 64; kt++) {
    int s0 = kt * 64;
    int cb = kt & 1;
    if (kt + 1 < S_LEN / 64) stage(s0 + 64, cb ^ 1);   // async prefetch, drained by end barrier

    // S = Q K^T  (M=32 per wave, N=64, K=64)
    f32x4 sacc[2][4] = {};
    #pragma unroll
    for (int kk = 0; kk < 2; kk++) {
      bf16x8 bk[4];
      #pragma unroll
      for (int nt = 0; nt < 4; nt++) bk[nt] = *(const bf16x8*)&Ks[cb][(nt * 16 + c16) * 72 + kk * 32 + quad * 8];
      #pragma unroll
      for (int mt = 0; mt < 2; mt++)
        #pragma unroll
        for (int nt = 0; nt < 4; nt++)
          sacc[mt][nt] = __builtin_amdgcn_mfma_f32_16x16x32_bf16(aq[mt][kk], bk[nt], sacc[mt][nt], 0, 0, 0);
    }

    // P = exp(S + maskterm); wave-private Ps rows (same-wave DS order, no barrier)
    #pragma unroll
    for (int nt = 0; nt < 4; nt++) {
      float madd = Msall[s0 + nt * 16 + c16];
      #pragma unroll
      for (int mt = 0; mt < 2; mt++)
        #pragma unroll
        for (int r = 0; r < 4; r++) {
          float p = __expf(sacc[mt][nt][r] + madd);
          lsum[mt][r] += p;
          Ps[qw0 + mt * 16 + quad * 4 + r][nt * 16 + c16] = f2bf(p);
        }
    }

    // O += P V
    #pragma unroll
    for (int kk = 0; kk < 2; kk++) {
      bf16x8 pa[2], vb[4];
      #pragma unroll
      for (int mt = 0; mt < 2; mt++) pa[mt] = *(const bf16x8*)&Ps[qw0 + mt * 16 + c16][kk * 32 + quad * 8];
      #pragma unroll
      for (int nt = 0; nt < 4; nt++) vb[nt] = *(const bf16x8*)&VTs[cb][(nt * 16 + c16) * 72 + kk * 32 + quad * 8];
      #pragma unroll
      for (int mt = 0; mt < 2; mt++)
        #pragma unroll
        for (int nt = 0; nt < 4; nt++)
          oacc[mt][nt] = __builtin_amdgcn_mfma_f32_16x16x32_bf16(pa[mt], vb[kk == 0 ? nt : nt], oacc[mt][nt], 0, 0, 0);
    }
    __syncthreads();      // (a) all reads of buf cb done -> reusable; (b) vmcnt(0) drains prefetch
  }

  // row-sum l: reduce across the 16 c16-lanes
  #pragma unroll
  for (int mt = 0; mt < 2; mt++)
    #pragma unroll
    for (int r = 0; r < 4; r++) {
      float v = lsum[mt][r];
      v += __shfl_xor(v, 1); v += __shfl_xor(v, 2); v += __shfl_xor(v, 4); v += __shfl_xor(v, 8);
      lsum[mt][r] = v;
    }

  u16* Obase = Om + (size_t)b * SH + (size_t)qb * 128 * HDIM + h * 64;
  #pragma unroll
  for (int mt = 0; mt < 2; mt++)
    #pragma unroll
    for (int nt = 0; nt < 4; nt++)
      #pragma unroll
      for (int r = 0; r < 4; r++) {
        int lr = qw0 + mt * 16 + quad * 4 + r;
        Obase[(size_t)lr * HDIM + nt * 16 + c16] = f2bf(oacc[mt][nt][r] / lsum[mt][r]);
      }
}

extern "C" void kernel_launch(void* const* d_in, const int* in_sizes, int n_in,
                              void* d_out, int out_size, void* d_ws, size_t ws_size,
                              hipStream_t stream)
{
  (void)in_sizes; (void)n_in; (void)out_size; (void)ws_size;
  const float* q_in = (const float*)d_in[0];
  const float* k_in = (const float*)d_in[1];
  const float* v_in = (const float*)d_in[2];
  const float* mask = (const float*)d_in[3];
  const float* wq   = (const float*)d_in[4];
  const float* bq   = (const float*)d_in[5];
  const float* wk   = (const float*)d_in[6];
  const float* bk   = (const float*)d_in[7];
  const float* wv   = (const float*)d_in[8];
  const float* bv   = (const float*)d_in[9];
  const float* wo   = (const float*)d_in[10];
  const float* bo   = (const float*)d_in[11];

  u16* ws  = (u16*)d_ws;                 // bf16 elems: 4x1M wt + 3x4M in + 5x4M acts = 72 MB
  u16* wqt = ws;
  u16* wkt = wqt + (1u << 20);
  u16* wvt = wkt + (1u << 20);
  u16* wot = wvt + (1u << 20);
  u16* qi_ = wot + (1u << 20);
  u16* ki_ = qi_ + (4u << 20);
  u16* vi_ = ki_ + (4u << 20);
  u16* qb_ = vi_ + (4u << 20);
  u16* kb_ = qb_ + (4u << 20);
  u16* vb_ = kb_ + (4u << 20);
  u16* vtb = vb_ + (4u << 20);
  u16* ob_ = vtb + (4u << 20);

  dim3 blk(256);
  k_cvt3<<<dim3(2048, 3), blk, 0, stream>>>(q_in, k_in, v_in, qi_, ki_, vi_);
  k_tr_w4<<<dim3(16, 16, 4), blk, 0, stream>>>(wq, wk, wv, wo, wqt, wkt, wvt, wot);
  k_gemm_qkv<<<dim3(32, 8, 3), blk, 0, stream>>>(qi_, ki_, vi_, wqt, wkt, wvt, bq, bk, bv, qb_, kb_, vb_);
  k_tr_v<<<dim3(32, 32), blk, 0, stream>>>(vb_, vtb);
  k_attn<<<dim3(16, 16, 2), blk, 0, stream>>>(qb_, kb_, vtb, mask, ob_);
  k_gemm_o<<<dim3(32, 16), blk, 0, stream>>>(ob_, wot, bo, (float*)d_out);
}